// Round 15
// baseline (195.904 us; speedup 1.0000x reference)
//
#include <hip/hip_runtime.h>

#define H 64
#define ACHUNK 4096

typedef __attribute__((ext_vector_type(8))) __bf16 bf16x8;
typedef __attribute__((ext_vector_type(4))) float f32x4;
union U16 { uint4 u; bf16x8 b; };

__device__ __forceinline__ float silu_f(float v) {
    return v * __builtin_amdgcn_rcpf(1.0f + __expf(-v));
}

__device__ __forceinline__ unsigned bf16r(float f) {
    unsigned b = __float_as_uint(f);
    return (b + 0x7fffu + ((b >> 16) & 1u)) >> 16;   // RTNE (inputs finite)
}
__device__ __forceinline__ unsigned pack2(float lo, float hi) {
    return bf16r(lo) | (bf16r(hi) << 16);
}
__device__ __forceinline__ float4 unpack4(uint2 u) {
    float4 r;
    r.x = __uint_as_float(u.x << 16);
    r.y = __uint_as_float(u.x & 0xffff0000u);
    r.z = __uint_as_float(u.y << 16);
    r.w = __uint_as_float(u.y & 0xffff0000u);
    return r;
}

// ---------------- Fused: weight pre-pack (blocks 0-127) + bucket-count partials (128-255) ----------
__global__ __launch_bounds__(256) void k_prep(
    const float* __restrict__ embW, const float* __restrict__ iW, const float* __restrict__ uW,
    unsigned short* __restrict__ embF, unsigned short* __restrict__ iF, unsigned short* __restrict__ uF,
    const int* __restrict__ src, int* __restrict__ bpart, int E)
{
    if (blockIdx.x < 128) {
        int t = blockIdx.x * 256 + threadIdx.x;
        if (t < 8192) {   // embF: ct(4) x kt(4) x lane(64) x e(8); K=128 pad of 121, N=64
            int e = t & 7, l = (t >> 3) & 63, kt = (t >> 9) & 3, ct = (t >> 11) & 3;
            int k = kt * 32 + (l >> 4) * 8 + e;
            int n = ct * 16 + (l & 15);
            float v = (k < 121) ? embW[k * 64 + n] : 0.f;
            embF[t] = (unsigned short)bf16r(v);
        }
        if (t < 16384) {  // uF: layer(4) x ct(4) x kt(2) x lane(64) x e(8)
            int e = t & 7, l = (t >> 3) & 63, kt = (t >> 9) & 1, ct = (t >> 10) & 3, ly = (t >> 12) & 3;
            int k = kt * 32 + (l >> 4) * 8 + e;
            int n = ct * 16 + (l & 15);
            uF[t] = (unsigned short)bf16r(uW[(size_t)ly * 4096 + k * 64 + n]);
        }
        if (t < 32768) {  // iF: layer(4) x ct(8) x kt(2) x lane(64) x e(8); [Wt|Wb]
            int e = t & 7, l = (t >> 3) & 63, kt = (t >> 9) & 1, ct = (t >> 10) & 7, ly = (t >> 13) & 3;
            int k = kt * 32 + (l >> 4) * 8 + e;
            int n = ct * 16 + (l & 15);
            const float* W = iW + (size_t)ly * 128 * 64;
            float v = (n < 64) ? W[k * 64 + n] : W[(64 + k) * 64 + (n - 64)];
            iF[t] = (unsigned short)bf16r(v);
        }
    } else {
        __shared__ int lc[256];
        const int t = threadIdx.x;
        const int blk = blockIdx.x - 128;
        lc[t] = 0;
        __syncthreads();
        for (int e = blk * 256 + t; e < E; e += 128 * 256)
            atomicAdd(&lc[src[e] >> 8], 1);
        __syncthreads();
        bpart[blk * 256 + t] = lc[t];
    }
}

// reduce bpart -> exclusive bucket bases
__global__ __launch_bounds__(256) void k_bscan(const int* __restrict__ bpart,
                                               int* __restrict__ bbase, int* __restrict__ bcur,
                                               int NB, int E)
{
    __shared__ int s[256];
    const int t = threadIdx.x;
    int v = 0;
    for (int b = 0; b < 128; ++b) v += bpart[b * 256 + t];
    s[t] = v;
    __syncthreads();
    for (int off = 1; off < 256; off <<= 1) {
        int u = (t >= off) ? s[t - off] : 0;
        __syncthreads();
        s[t] += u;
        __syncthreads();
    }
    if (t < NB) {
        int ex = s[t] - v;
        bbase[t] = ex;
        bcur[t] = ex;
    }
    if (t == 0) bbase[NB] = E;
}

// Stage ACHUNK edges in LDS grouped by bucket; write each group contiguously.
__global__ __launch_bounds__(256) void k_bucketA(const int* __restrict__ src, const int* __restrict__ dst,
                                                 int* __restrict__ bcur, uint2* __restrict__ tmp, int E)
{
    __shared__ int lscan[256], lrun[256], gbase[256];
    __shared__ uint2 stage[ACHUNK];
    const int t = threadIdx.x;
    const int c0 = blockIdx.x * ACHUNK;
    const int cend = min(c0 + ACHUNK, E);
    const int n = cend - c0;
    lscan[t] = 0;
    __syncthreads();
    for (int i = c0 + t; i < cend; i += 256)
        atomicAdd(&lscan[src[i] >> 8], 1);
    __syncthreads();
    int v = lscan[t];
    __syncthreads();
    lscan[t] = v;
    __syncthreads();
    for (int off = 1; off < 256; off <<= 1) {
        int u = (t >= off) ? lscan[t - off] : 0;
        __syncthreads();
        lscan[t] += u;
        __syncthreads();
    }
    int ex = lscan[t] - v;
    lscan[t] = ex;
    lrun[t] = ex;
    if (v > 0) gbase[t] = atomicAdd(&bcur[t], v);
    __syncthreads();
    for (int i = c0 + t; i < cend; i += 256) {
        int s_ = src[i];
        int b = s_ >> 8;
        int p = atomicAdd(&lrun[b], 1);
        stage[p] = make_uint2((unsigned)s_, (unsigned)dst[i]);
    }
    __syncthreads();
    for (int i = t; i < n; i += 256) {
        uint2 e = stage[i];
        int b = (int)(e.x >> 8);
        tmp[gbase[b] + i - lscan[b]] = e;
    }
}

// ---------------- Fused CSR finalize (blocks 0..NB-1) + embed/layer-0 interact (blocks NB..) ----
struct SmemEmbed {
    float ot[32 * 68];                 // 8704 B (aliased with xin)
    unsigned short xbuf[32 * 72];      // 4608 B
};
struct SmemCsr { int lc[256]; int curL[256]; };
union SmemU { SmemEmbed e; SmemCsr c; };

__global__ __launch_bounds__(256) void k_csr_embed(
    // csr part
    const uint2* __restrict__ tmp, const int* __restrict__ bbase,
    int* __restrict__ rp, int* __restrict__ col, int NB, int E,
    // embed part
    const float* __restrict__ oneh, const float* __restrict__ pos,
    const uint4* __restrict__ Wf, const float* __restrict__ eb,
    const uint4* __restrict__ iFn, const float* __restrict__ ibn,
    float* __restrict__ x, float* __restrict__ x0,
    unsigned short* __restrict__ Aout, unsigned short* __restrict__ Bout, int N)
{
    __shared__ SmemU sm;
    const int t = threadIdx.x;
    if ((int)blockIdx.x < NB) {
        // ---- CSR: per-bucket hist + scan + rp + scatter (bucket-local => global offsets) ----
        int* lc = sm.c.lc;
        int* curL = sm.c.curL;
        const int b = blockIdx.x;
        lc[t] = 0;
        __syncthreads();
        const int beg = bbase[b], end = bbase[b + 1];
        for (int i = beg + t; i < end; i += 256)
            atomicAdd(&lc[tmp[i].x & 255], 1);
        __syncthreads();
        int v = lc[t];
        __syncthreads();
        for (int off = 1; off < 256; off <<= 1) {
            int u = (t >= off) ? lc[t - off] : 0;
            __syncthreads();
            lc[t] += u;
            __syncthreads();
        }
        const int r = beg + lc[t] - v;   // global CSR offset for node b*256+t
        const int node = b * 256 + t;
        if (node < N) rp[node] = r;
        if (node == 0) rp[N] = E;
        curL[t] = r;
        __syncthreads();
        for (int i = beg + t; i < end; i += 256) {
            uint2 e = tmp[i];
            int p = atomicAdd(&curL[e.x & 255], 1);
            col[p] = (int)e.y;
        }
        return;
    }
    // ---- embed + layer-0 interact ----
    float* ot = sm.e.ot;
    unsigned short* xbuf = sm.e.xbuf;
    unsigned short* xin = (unsigned short*)ot;   // 32*136 ushorts == 8704 B
    const int w = t >> 6, l = t & 63;
    const int n0 = ((int)blockIdx.x - NB) * 32;
    const int nvalid = min(32, N - n0);
    const int validf = nvalid * 118;
    {
        uint4* xz = (uint4*)xin;
        for (int i = t; i < 544; i += 256) xz[i] = make_uint4(0, 0, 0, 0);
    }
    __syncthreads();
    {
        const float4* oh4 = reinterpret_cast<const float4*>(oneh + (size_t)n0 * 118);
        for (int i = t; i < 944; i += 256) {
            int base = i * 4;
            if (base + 4 <= validf) {
                float4 v = oh4[i];
                #pragma unroll
                for (int c = 0; c < 4; ++c) {
                    int li = base + c;
                    int nd = li / 118, kk = li - nd * 118;
                    float vc = (c == 0) ? v.x : (c == 1) ? v.y : (c == 2) ? v.z : v.w;
                    xin[nd * 136 + kk] = (unsigned short)bf16r(vc);
                }
            } else if (base < validf) {
                for (int c = 0; c < 4 && base + c < validf; ++c) {
                    int li = base + c;
                    int nd = li / 118, kk = li - nd * 118;
                    xin[nd * 136 + kk] = (unsigned short)bf16r(oneh[(size_t)n0 * 118 + li]);
                }
            }
        }
        if (t < 96) {
            int nd = t / 3, c = t - nd * 3;
            if (nd < nvalid)
                xin[nd * 136 + 118 + c] = (unsigned short)bf16r(pos[(size_t)(n0 + nd) * 3 + c]);
        }
    }
    __syncthreads();
    const int rt = w & 1, ctb = (w >> 1) * 2;
    U16 af[4];
    #pragma unroll
    for (int kt = 0; kt < 4; ++kt)
        af[kt].u = *reinterpret_cast<const uint4*>(
            &xin[(rt * 16 + (l & 15)) * 136 + kt * 32 + (l >> 4) * 8]);
    f32x4 acc0 = {0.f, 0.f, 0.f, 0.f}, acc1 = {0.f, 0.f, 0.f, 0.f};
    #pragma unroll
    for (int kt = 0; kt < 4; ++kt) {
        U16 b0, b1;
        b0.u = Wf[((ctb + 0) * 4 + kt) * 64 + l];
        b1.u = Wf[((ctb + 1) * 4 + kt) * 64 + l];
        acc0 = __builtin_amdgcn_mfma_f32_16x16x32_bf16(af[kt].b, b0.b, acc0, 0, 0, 0);
        acc1 = __builtin_amdgcn_mfma_f32_16x16x32_bf16(af[kt].b, b1.b, acc1, 0, 0, 0);
    }
    __syncthreads();   // done with xin; reuse as ot
    #pragma unroll
    for (int r = 0; r < 4; ++r) {
        ot[(rt * 16 + (l >> 4) * 4 + r) * 68 + (ctb + 0) * 16 + (l & 15)] = acc0[r];
        ot[(rt * 16 + (l >> 4) * 4 + r) * 68 + (ctb + 1) * 16 + (l & 15)] = acc1[r];
    }
    __syncthreads();
    for (int v = t; v < 512; v += 256) {
        int node = v >> 4, q = v & 15;
        float4 bq = reinterpret_cast<const float4*>(eb)[q];
        float* p = &ot[node * 68 + q * 4];
        float4 o;
        o.x = silu_f(p[0] + bq.x); o.y = silu_f(p[1] + bq.y);
        o.z = silu_f(p[2] + bq.z); o.w = silu_f(p[3] + bq.w);
        int g = n0 + node;
        if (g < N) {
            reinterpret_cast<float4*>(x)[(size_t)g * 16 + q] = o;
            reinterpret_cast<float4*>(x0)[(size_t)g * 16 + q] = o;
        }
        p[0] = o.x; p[1] = o.y; p[2] = o.z; p[3] = o.w;
    }
    __syncthreads();
    {
        int node = t >> 3, j = t & 7;
        const float* p = &ot[node * 68 + j * 8];
        uint4 o;
        o.x = pack2(p[0], p[1]); o.y = pack2(p[2], p[3]);
        o.z = pack2(p[4], p[5]); o.w = pack2(p[6], p[7]);
        *reinterpret_cast<uint4*>(&xbuf[node * 72 + j * 8]) = o;
    }
    __syncthreads();
    #pragma unroll
    for (int mt = 0; mt < 2; ++mt) {
        U16 a0, a1, bA0, bA1, bB0, bB1;
        a0.u = *reinterpret_cast<const uint4*>(&xbuf[(mt * 16 + (l & 15)) * 72 + (l >> 4) * 8]);
        a1.u = *reinterpret_cast<const uint4*>(&xbuf[(mt * 16 + (l & 15)) * 72 + 32 + (l >> 4) * 8]);
        bA0.u = iFn[(w * 2 + 0) * 64 + l];
        bA1.u = iFn[(w * 2 + 1) * 64 + l];
        bB0.u = iFn[((w + 4) * 2 + 0) * 64 + l];
        bB1.u = iFn[((w + 4) * 2 + 1) * 64 + l];
        f32x4 accA = {0.f, 0.f, 0.f, 0.f}, accB = {0.f, 0.f, 0.f, 0.f};
        accA = __builtin_amdgcn_mfma_f32_16x16x32_bf16(a0.b, bA0.b, accA, 0, 0, 0);
        accA = __builtin_amdgcn_mfma_f32_16x16x32_bf16(a1.b, bA1.b, accA, 0, 0, 0);
        accB = __builtin_amdgcn_mfma_f32_16x16x32_bf16(a0.b, bB0.b, accB, 0, 0, 0);
        accB = __builtin_amdgcn_mfma_f32_16x16x32_bf16(a1.b, bB1.b, accB, 0, 0, 0);
        const int colA = w * 16 + (l & 15);
        const float biasA = ibn[colA];
        #pragma unroll
        for (int r = 0; r < 4; ++r) {
            int gn = n0 + mt * 16 + (l >> 4) * 4 + r;
            if (gn < N) {
                Aout[(size_t)gn * 64 + colA] = (unsigned short)bf16r(accA[r] + biasA);
                Bout[(size_t)gn * 64 + colA] = (unsigned short)bf16r(accB[r]);
            }
        }
    }
}

// ---------------- Fused edge + MFMA update + next-layer interact (+ final out) ----------------
// 16-lane groups; gather loop tiers: 8-wide, 4-wide, scalar tail (8 gathers in flight max).
template <bool LAST>
__global__ __launch_bounds__(256) void k_edge_upd(
    const int* __restrict__ rp, const int* __restrict__ col,
    const unsigned* __restrict__ Ab, const unsigned* __restrict__ Bb,
    float* __restrict__ x,
    const uint4* __restrict__ uFf, const float* __restrict__ ub,
    const uint4* __restrict__ iFn, const float* __restrict__ ibn,
    unsigned short* __restrict__ Aout, unsigned short* __restrict__ Bout,
    const float* __restrict__ x0, const float* __restrict__ oW, const float* __restrict__ ob,
    float* __restrict__ out, int N)
{
    __shared__ unsigned short vb[16 * 72];   // bf16 rows, stride 72
    __shared__ float sv[16 * 68];            // silu(update) rows, stride 68
    const int t = threadIdx.x;
    const int g = t >> 4, q = t & 15;
    const int w = t >> 6, l = t & 63;
    const int node = blockIdx.x * 16 + g;
    const bool valid = node < N;
    const size_t nidx = (size_t)(valid ? node : 0) * 16 + q;
    const uint2* __restrict__ Avb = reinterpret_cast<const uint2*>(Ab);
    const uint2* __restrict__ Bv = reinterpret_cast<const uint2*>(Bb);
    float4* __restrict__ Xv = reinterpret_cast<float4*>(x);

    const float4 a = unpack4(Avb[nidx]);
    const float4 xq = Xv[nidx];
    const int beg = valid ? rp[node] : 0;
    const int end = valid ? rp[node + 1] : 0;

    float4 acc = make_float4(0.f, 0.f, 0.f, 0.f);
    int j = beg;
    for (; j + 8 <= end; j += 8) {
        int d0 = col[j],     d1 = col[j + 1], d2 = col[j + 2], d3 = col[j + 3];
        int d4 = col[j + 4], d5 = col[j + 5], d6 = col[j + 6], d7 = col[j + 7];
        float4 b0 = unpack4(Bv[(size_t)d0 * 16 + q]);
        float4 b1 = unpack4(Bv[(size_t)d1 * 16 + q]);
        float4 b2 = unpack4(Bv[(size_t)d2 * 16 + q]);
        float4 b3 = unpack4(Bv[(size_t)d3 * 16 + q]);
        float4 b4 = unpack4(Bv[(size_t)d4 * 16 + q]);
        float4 b5 = unpack4(Bv[(size_t)d5 * 16 + q]);
        float4 b6 = unpack4(Bv[(size_t)d6 * 16 + q]);
        float4 b7 = unpack4(Bv[(size_t)d7 * 16 + q]);
        acc.x += silu_f(a.x + b0.x) + silu_f(a.x + b1.x) + silu_f(a.x + b2.x) + silu_f(a.x + b3.x)
               + silu_f(a.x + b4.x) + silu_f(a.x + b5.x) + silu_f(a.x + b6.x) + silu_f(a.x + b7.x);
        acc.y += silu_f(a.y + b0.y) + silu_f(a.y + b1.y) + silu_f(a.y + b2.y) + silu_f(a.y + b3.y)
               + silu_f(a.y + b4.y) + silu_f(a.y + b5.y) + silu_f(a.y + b6.y) + silu_f(a.y + b7.y);
        acc.z += silu_f(a.z + b0.z) + silu_f(a.z + b1.z) + silu_f(a.z + b2.z) + silu_f(a.z + b3.z)
               + silu_f(a.z + b4.z) + silu_f(a.z + b5.z) + silu_f(a.z + b6.z) + silu_f(a.z + b7.z);
        acc.w += silu_f(a.w + b0.w) + silu_f(a.w + b1.w) + silu_f(a.w + b2.w) + silu_f(a.w + b3.w)
               + silu_f(a.w + b4.w) + silu_f(a.w + b5.w) + silu_f(a.w + b6.w) + silu_f(a.w + b7.w);
    }
    for (; j + 4 <= end; j += 4) {
        int d0 = col[j], d1 = col[j + 1], d2 = col[j + 2], d3 = col[j + 3];
        float4 b0 = unpack4(Bv[(size_t)d0 * 16 + q]);
        float4 b1 = unpack4(Bv[(size_t)d1 * 16 + q]);
        float4 b2 = unpack4(Bv[(size_t)d2 * 16 + q]);
        float4 b3 = unpack4(Bv[(size_t)d3 * 16 + q]);
        acc.x += silu_f(a.x + b0.x) + silu_f(a.x + b1.x) + silu_f(a.x + b2.x) + silu_f(a.x + b3.x);
        acc.y += silu_f(a.y + b0.y) + silu_f(a.y + b1.y) + silu_f(a.y + b2.y) + silu_f(a.y + b3.y);
        acc.z += silu_f(a.z + b0.z) + silu_f(a.z + b1.z) + silu_f(a.z + b2.z) + silu_f(a.z + b3.z);
        acc.w += silu_f(a.w + b0.w) + silu_f(a.w + b1.w) + silu_f(a.w + b2.w) + silu_f(a.w + b3.w);
    }
    for (; j < end; ++j) {
        int d = col[j];
        float4 b = unpack4(Bv[(size_t)d * 16 + q]);
        acc.x += silu_f(a.x + b.x); acc.y += silu_f(a.y + b.y);
        acc.z += silu_f(a.z + b.z); acc.w += silu_f(a.w + b.w);
    }
    float4 v;
    v.x = fmaf(0.25f, acc.x, xq.x); v.y = fmaf(0.25f, acc.y, xq.y);
    v.z = fmaf(0.25f, acc.z, xq.z); v.w = fmaf(0.25f, acc.w, xq.w);
    {
        uint2 vo;
        vo.x = pack2(v.x, v.y);
        vo.y = pack2(v.z, v.w);
        *reinterpret_cast<uint2*>(&vb[g * 72 + q * 4]) = vo;
    }
    __syncthreads();
    {
        U16 a0, a1, b0, b1;
        a0.u = *reinterpret_cast<const uint4*>(&vb[(l & 15) * 72 + (l >> 4) * 8]);
        a1.u = *reinterpret_cast<const uint4*>(&vb[(l & 15) * 72 + 32 + (l >> 4) * 8]);
        b0.u = uFf[(w * 2 + 0) * 64 + l];
        b1.u = uFf[(w * 2 + 1) * 64 + l];
        f32x4 uacc = {0.f, 0.f, 0.f, 0.f};
        uacc = __builtin_amdgcn_mfma_f32_16x16x32_bf16(a0.b, b0.b, uacc, 0, 0, 0);
        uacc = __builtin_amdgcn_mfma_f32_16x16x32_bf16(a1.b, b1.b, uacc, 0, 0, 0);
        const int h = w * 16 + (l & 15);
        const float ubh = ub[h];
        #pragma unroll
        for (int r = 0; r < 4; ++r)
            sv[((l >> 4) * 4 + r) * 68 + h] = silu_f(uacc[r] + ubh);
    }
    __syncthreads();
    const float4 s = *reinterpret_cast<const float4*>(&sv[g * 68 + q * 4]);
    float4 xn;
    xn.x = xq.x + s.x; xn.y = xq.y + s.y;
    xn.z = xq.z + s.z; xn.w = xq.w + s.w;
    if (valid && !LAST) Xv[nidx] = xn;
    if (!LAST) {
        uint2 xo;
        xo.x = pack2(xn.x, xn.y);
        xo.y = pack2(xn.z, xn.w);
        *reinterpret_cast<uint2*>(&vb[g * 72 + q * 4]) = xo;
        __syncthreads();
        U16 a0, a1, bA0, bA1, bB0, bB1;
        a0.u = *reinterpret_cast<const uint4*>(&vb[(l & 15) * 72 + (l >> 4) * 8]);
        a1.u = *reinterpret_cast<const uint4*>(&vb[(l & 15) * 72 + 32 + (l >> 4) * 8]);
        bA0.u = iFn[(w * 2 + 0) * 64 + l];
        bA1.u = iFn[(w * 2 + 1) * 64 + l];
        bB0.u = iFn[((w + 4) * 2 + 0) * 64 + l];
        bB1.u = iFn[((w + 4) * 2 + 1) * 64 + l];
        f32x4 accA = {0.f, 0.f, 0.f, 0.f}, accB = {0.f, 0.f, 0.f, 0.f};
        accA = __builtin_amdgcn_mfma_f32_16x16x32_bf16(a0.b, bA0.b, accA, 0, 0, 0);
        accA = __builtin_amdgcn_mfma_f32_16x16x32_bf16(a1.b, bA1.b, accA, 0, 0, 0);
        accB = __builtin_amdgcn_mfma_f32_16x16x32_bf16(a0.b, bB0.b, accB, 0, 0, 0);
        accB = __builtin_amdgcn_mfma_f32_16x16x32_bf16(a1.b, bB1.b, accB, 0, 0, 0);
        const int colA = w * 16 + (l & 15);
        const float biasA = ibn[colA];
        #pragma unroll
        for (int r = 0; r < 4; ++r) {
            int gn = blockIdx.x * 16 + (l >> 4) * 4 + r;
            if (gn < N) {
                Aout[(size_t)gn * 64 + colA] = (unsigned short)bf16r(accA[r] + biasA);
                Bout[(size_t)gn * 64 + colA] = (unsigned short)bf16r(accB[r]);
            }
        }
    } else {
        const float4 x0q = reinterpret_cast<const float4*>(x0)[nidx];
        float f0 = xn.x + x0q.x, f1 = xn.y + x0q.y, f2 = xn.z + x0q.z, f3 = xn.w + x0q.w;
        float p0 = 0.f, p1 = 0.f, p2 = 0.f;
        const int k0 = 4 * q;
        p0 = fmaf(f0, oW[(k0 + 0) * 3 + 0], p0); p1 = fmaf(f0, oW[(k0 + 0) * 3 + 1], p1); p2 = fmaf(f0, oW[(k0 + 0) * 3 + 2], p2);
        p0 = fmaf(f1, oW[(k0 + 1) * 3 + 0], p0); p1 = fmaf(f1, oW[(k0 + 1) * 3 + 1], p1); p2 = fmaf(f1, oW[(k0 + 1) * 3 + 2], p2);
        p0 = fmaf(f2, oW[(k0 + 2) * 3 + 0], p0); p1 = fmaf(f2, oW[(k0 + 2) * 3 + 1], p1); p2 = fmaf(f2, oW[(k0 + 2) * 3 + 2], p2);
        p0 = fmaf(f3, oW[(k0 + 3) * 3 + 0], p0); p1 = fmaf(f3, oW[(k0 + 3) * 3 + 1], p1); p2 = fmaf(f3, oW[(k0 + 3) * 3 + 2], p2);
        #pragma unroll
        for (int off = 8; off; off >>= 1) {
            p0 += __shfl_xor(p0, off, 16);
            p1 += __shfl_xor(p1, off, 16);
            p2 += __shfl_xor(p2, off, 16);
        }
        if (valid && q == 0) {
            out[node * 3 + 0] = p0 + ob[0];
            out[node * 3 + 1] = p1 + ob[1];
            out[node * 3 + 2] = p2 + ob[2];
        }
    }
}

extern "C" void kernel_launch(void* const* d_in, const int* in_sizes, int n_in,
                              void* d_out, int out_size, void* d_ws, size_t ws_size,
                              hipStream_t stream)
{
    const float* oneh = (const float*)d_in[0];
    const float* pos  = (const float*)d_in[1];
    const int*   ei   = (const int*)d_in[2];
    const float* embW = (const float*)d_in[3];
    const float* embB = (const float*)d_in[4];
    const float* iW   = (const float*)d_in[5];   // [4][128][64]
    const float* iB   = (const float*)d_in[6];   // [4][64]
    const float* uW   = (const float*)d_in[7];   // [4][64][64]
    const float* uB   = (const float*)d_in[8];   // [4][64]
    const float* oW   = (const float*)d_in[9];   // [64][3]
    const float* oB   = (const float*)d_in[10];  // [3]

    const int N = in_sizes[0] / 118;
    const int E = in_sizes[2] / 2;
    const int* src = ei;
    const int* dst = ei + E;

    float* ws = (float*)d_ws;
    const size_t NH = (size_t)N * H;
    float* x  = ws;
    float* x0 = ws + NH;
    unsigned short* A0   = (unsigned short*)(ws + 2 * NH);   // NH bf16
    unsigned short* A1   = A0 + NH;                           // NH bf16
    unsigned short* Bb0  = A1 + NH;                           // NH bf16
    unsigned short* Bb1  = Bb0 + NH;                          // NH bf16
    unsigned short* embF = Bb1 + NH;                          // 8192
    unsigned short* iF   = embF + 8192;                       // 32768
    unsigned short* uFf  = iF + 32768;                        // 16384
    int* ibase = (int*)(uFf + 16384);
    int* rp    = ibase;               // N+1
    int* col   = ibase + N + 1;       // E
    int* bbase = col + E;             // NB+1
    int* bcur  = bbase + 257;         // NB
    int* bpart = bcur + 256;          // 128*256
    uint2* tmp = (uint2*)(bpart + 128 * 256);  // E (own buffer: embed runs concurrently)

    const int nbm = (N + 31) / 32;
    const int nbf = (N + 15) / 16;
    const int NB  = (N + 255) / 256;

    // prep (weight pack || bucket partial counts) -> bucket bases -> bucketize
    k_prep<<<256, 256, 0, stream>>>(embW, iW, uW, embF, iF, uFf, src, bpart, E);
    k_bscan<<<1, 256, 0, stream>>>(bpart, bbase, bcur, NB, E);
    k_bucketA<<<(E + ACHUNK - 1) / ACHUNK, 256, 0, stream>>>(src, dst, bcur, tmp, E);
    // CSR finalize (bucket-local scan gives global offsets) || embed + layer-0 interact
    k_csr_embed<<<NB + nbm, 256, 0, stream>>>(tmp, bbase, rp, col, NB, E,
                                              oneh, pos, (const uint4*)embF, embB,
                                              (const uint4*)iF, iB, x, x0, A0, Bb0, N);

    unsigned short* Ain[4]  = {A0, A1, A0, A1};
    unsigned short* Aout[4] = {A1, A0, A1, A0};
    unsigned short* Bin[4]  = {Bb0, Bb1, Bb0, Bb1};
    unsigned short* Bout[4] = {Bb1, Bb0, Bb1, Bb0};

    for (int l = 0; l < 4; ++l) {
        const uint4* uFl = (const uint4*)(uFf + (size_t)l * 4096);
        const uint4* iFn = (l < 3) ? (const uint4*)(iF + (size_t)(l + 1) * 8192) : (const uint4*)iF;
        const float* ibn = (l < 3) ? iB + (l + 1) * 64 : iB;
        if (l < 3)
            k_edge_upd<false><<<nbf, 256, 0, stream>>>(rp, col, (const unsigned*)Ain[l], (const unsigned*)Bin[l], x,
                uFl, uB + l * 64, iFn, ibn, Aout[l], Bout[l], x0, oW, oB, (float*)d_out, N);
        else
            k_edge_upd<true><<<nbf, 256, 0, stream>>>(rp, col, (const unsigned*)Ain[l], (const unsigned*)Bin[l], x,
                uFl, uB + l * 64, iFn, ibn, Aout[l], Bout[l], x0, oW, oB, (float*)d_out, N);
    }
}

// Round 16
// 174.950 us; speedup vs baseline: 1.1198x; 1.1198x over previous
//
#include <hip/hip_runtime.h>

#define H 64
#define ACHUNK 4096

typedef __attribute__((ext_vector_type(8))) __bf16 bf16x8;
typedef __attribute__((ext_vector_type(4))) float f32x4;
union U16 { uint4 u; bf16x8 b; };

__device__ __forceinline__ float silu_f(float v) {
    return v * __builtin_amdgcn_rcpf(1.0f + __expf(-v));
}

__device__ __forceinline__ unsigned bf16r(float f) {
    unsigned b = __float_as_uint(f);
    return (b + 0x7fffu + ((b >> 16) & 1u)) >> 16;   // RTNE (inputs finite)
}
__device__ __forceinline__ unsigned pack2(float lo, float hi) {
    return bf16r(lo) | (bf16r(hi) << 16);
}
__device__ __forceinline__ float4 unpack4(uint2 u) {
    float4 r;
    r.x = __uint_as_float(u.x << 16);
    r.y = __uint_as_float(u.x & 0xffff0000u);
    r.z = __uint_as_float(u.y << 16);
    r.w = __uint_as_float(u.y & 0xffff0000u);
    return r;
}

// ---------------- Fused: weight pre-pack (blocks 0-127) + bucket-count partials (128-255) ----------
__global__ __launch_bounds__(256) void k_prep(
    const float* __restrict__ embW, const float* __restrict__ iW, const float* __restrict__ uW,
    unsigned short* __restrict__ embF, unsigned short* __restrict__ iF, unsigned short* __restrict__ uF,
    const int* __restrict__ src, int* __restrict__ bpart, int E)
{
    if (blockIdx.x < 128) {
        int t = blockIdx.x * 256 + threadIdx.x;
        if (t < 8192) {   // embF: ct(4) x kt(4) x lane(64) x e(8); K=128 pad of 121, N=64
            int e = t & 7, l = (t >> 3) & 63, kt = (t >> 9) & 3, ct = (t >> 11) & 3;
            int k = kt * 32 + (l >> 4) * 8 + e;
            int n = ct * 16 + (l & 15);
            float v = (k < 121) ? embW[k * 64 + n] : 0.f;
            embF[t] = (unsigned short)bf16r(v);
        }
        if (t < 16384) {  // uF: layer(4) x ct(4) x kt(2) x lane(64) x e(8)
            int e = t & 7, l = (t >> 3) & 63, kt = (t >> 9) & 1, ct = (t >> 10) & 3, ly = (t >> 12) & 3;
            int k = kt * 32 + (l >> 4) * 8 + e;
            int n = ct * 16 + (l & 15);
            uF[t] = (unsigned short)bf16r(uW[(size_t)ly * 4096 + k * 64 + n]);
        }
        if (t < 32768) {  // iF: layer(4) x ct(8) x kt(2) x lane(64) x e(8); [Wt|Wb]
            int e = t & 7, l = (t >> 3) & 63, kt = (t >> 9) & 1, ct = (t >> 10) & 7, ly = (t >> 13) & 3;
            int k = kt * 32 + (l >> 4) * 8 + e;
            int n = ct * 16 + (l & 15);
            const float* W = iW + (size_t)ly * 128 * 64;
            float v = (n < 64) ? W[k * 64 + n] : W[(64 + k) * 64 + (n - 64)];
            iF[t] = (unsigned short)bf16r(v);
        }
    } else {
        __shared__ int lc[256];
        const int t = threadIdx.x;
        const int blk = blockIdx.x - 128;
        lc[t] = 0;
        __syncthreads();
        for (int e = blk * 256 + t; e < E; e += 128 * 256)
            atomicAdd(&lc[src[e] >> 8], 1);
        __syncthreads();
        bpart[blk * 256 + t] = lc[t];
    }
}

// reduce bpart -> exclusive bucket bases
__global__ __launch_bounds__(256) void k_bscan(const int* __restrict__ bpart,
                                               int* __restrict__ bbase, int* __restrict__ bcur,
                                               int NB, int E)
{
    __shared__ int s[256];
    const int t = threadIdx.x;
    int v = 0;
    for (int b = 0; b < 128; ++b) v += bpart[b * 256 + t];
    s[t] = v;
    __syncthreads();
    for (int off = 1; off < 256; off <<= 1) {
        int u = (t >= off) ? s[t - off] : 0;
        __syncthreads();
        s[t] += u;
        __syncthreads();
    }
    if (t < NB) {
        int ex = s[t] - v;
        bbase[t] = ex;
        bcur[t] = ex;
    }
    if (t == 0) bbase[NB] = E;
}

// Stage ACHUNK edges in LDS grouped by bucket; write each group contiguously.
__global__ __launch_bounds__(256) void k_bucketA(const int* __restrict__ src, const int* __restrict__ dst,
                                                 int* __restrict__ bcur, uint2* __restrict__ tmp, int E)
{
    __shared__ int lscan[256], lrun[256], gbase[256];
    __shared__ uint2 stage[ACHUNK];
    const int t = threadIdx.x;
    const int c0 = blockIdx.x * ACHUNK;
    const int cend = min(c0 + ACHUNK, E);
    const int n = cend - c0;
    lscan[t] = 0;
    __syncthreads();
    for (int i = c0 + t; i < cend; i += 256)
        atomicAdd(&lscan[src[i] >> 8], 1);
    __syncthreads();
    int v = lscan[t];
    __syncthreads();
    lscan[t] = v;
    __syncthreads();
    for (int off = 1; off < 256; off <<= 1) {
        int u = (t >= off) ? lscan[t - off] : 0;
        __syncthreads();
        lscan[t] += u;
        __syncthreads();
    }
    int ex = lscan[t] - v;
    lscan[t] = ex;
    lrun[t] = ex;
    if (v > 0) gbase[t] = atomicAdd(&bcur[t], v);
    __syncthreads();
    for (int i = c0 + t; i < cend; i += 256) {
        int s_ = src[i];
        int b = s_ >> 8;
        int p = atomicAdd(&lrun[b], 1);
        stage[p] = make_uint2((unsigned)s_, (unsigned)dst[i]);
    }
    __syncthreads();
    for (int i = t; i < n; i += 256) {
        uint2 e = stage[i];
        int b = (int)(e.x >> 8);
        tmp[gbase[b] + i - lscan[b]] = e;
    }
}

// ---------------- Fused CSR finalize (blocks 0..NB-1) + embed/layer-0 interact (blocks NB..) ----
struct SmemEmbed {
    float ot[32 * 68];                 // 8704 B (aliased with xin)
    unsigned short xbuf[32 * 72];      // 4608 B
};
struct SmemCsr { int lc[256]; int curL[256]; };
union SmemU { SmemEmbed e; SmemCsr c; };

__global__ __launch_bounds__(256) void k_csr_embed(
    // csr part
    const uint2* __restrict__ tmp, const int* __restrict__ bbase,
    int* __restrict__ rp, int* __restrict__ col, int NB, int E,
    // embed part
    const float* __restrict__ oneh, const float* __restrict__ pos,
    const uint4* __restrict__ Wf, const float* __restrict__ eb,
    const uint4* __restrict__ iFn, const float* __restrict__ ibn,
    float* __restrict__ x, float* __restrict__ x0,
    unsigned short* __restrict__ Aout, unsigned short* __restrict__ Bout, int N)
{
    __shared__ SmemU sm;
    const int t = threadIdx.x;
    if ((int)blockIdx.x < NB) {
        // ---- CSR: per-bucket hist + scan + rp + scatter (bucket-local => global offsets) ----
        int* lc = sm.c.lc;
        int* curL = sm.c.curL;
        const int b = blockIdx.x;
        lc[t] = 0;
        __syncthreads();
        const int beg = bbase[b], end = bbase[b + 1];
        for (int i = beg + t; i < end; i += 256)
            atomicAdd(&lc[tmp[i].x & 255], 1);
        __syncthreads();
        int v = lc[t];
        __syncthreads();
        for (int off = 1; off < 256; off <<= 1) {
            int u = (t >= off) ? lc[t - off] : 0;
            __syncthreads();
            lc[t] += u;
            __syncthreads();
        }
        const int r = beg + lc[t] - v;   // global CSR offset for node b*256+t
        const int node = b * 256 + t;
        if (node < N) rp[node] = r;
        if (node == 0) rp[N] = E;
        curL[t] = r;
        __syncthreads();
        for (int i = beg + t; i < end; i += 256) {
            uint2 e = tmp[i];
            int p = atomicAdd(&curL[e.x & 255], 1);
            col[p] = (int)e.y;
        }
        return;
    }
    // ---- embed + layer-0 interact ----
    float* ot = sm.e.ot;
    unsigned short* xbuf = sm.e.xbuf;
    unsigned short* xin = (unsigned short*)ot;   // 32*136 ushorts == 8704 B
    const int w = t >> 6, l = t & 63;
    const int n0 = ((int)blockIdx.x - NB) * 32;
    const int nvalid = min(32, N - n0);
    const int validf = nvalid * 118;
    {
        uint4* xz = (uint4*)xin;
        for (int i = t; i < 544; i += 256) xz[i] = make_uint4(0, 0, 0, 0);
    }
    __syncthreads();
    {
        const float4* oh4 = reinterpret_cast<const float4*>(oneh + (size_t)n0 * 118);
        for (int i = t; i < 944; i += 256) {
            int base = i * 4;
            if (base + 4 <= validf) {
                float4 v = oh4[i];
                #pragma unroll
                for (int c = 0; c < 4; ++c) {
                    int li = base + c;
                    int nd = li / 118, kk = li - nd * 118;
                    float vc = (c == 0) ? v.x : (c == 1) ? v.y : (c == 2) ? v.z : v.w;
                    xin[nd * 136 + kk] = (unsigned short)bf16r(vc);
                }
            } else if (base < validf) {
                for (int c = 0; c < 4 && base + c < validf; ++c) {
                    int li = base + c;
                    int nd = li / 118, kk = li - nd * 118;
                    xin[nd * 136 + kk] = (unsigned short)bf16r(oneh[(size_t)n0 * 118 + li]);
                }
            }
        }
        if (t < 96) {
            int nd = t / 3, c = t - nd * 3;
            if (nd < nvalid)
                xin[nd * 136 + 118 + c] = (unsigned short)bf16r(pos[(size_t)(n0 + nd) * 3 + c]);
        }
    }
    __syncthreads();
    const int rt = w & 1, ctb = (w >> 1) * 2;
    U16 af[4];
    #pragma unroll
    for (int kt = 0; kt < 4; ++kt)
        af[kt].u = *reinterpret_cast<const uint4*>(
            &xin[(rt * 16 + (l & 15)) * 136 + kt * 32 + (l >> 4) * 8]);
    f32x4 acc0 = {0.f, 0.f, 0.f, 0.f}, acc1 = {0.f, 0.f, 0.f, 0.f};
    #pragma unroll
    for (int kt = 0; kt < 4; ++kt) {
        U16 b0, b1;
        b0.u = Wf[((ctb + 0) * 4 + kt) * 64 + l];
        b1.u = Wf[((ctb + 1) * 4 + kt) * 64 + l];
        acc0 = __builtin_amdgcn_mfma_f32_16x16x32_bf16(af[kt].b, b0.b, acc0, 0, 0, 0);
        acc1 = __builtin_amdgcn_mfma_f32_16x16x32_bf16(af[kt].b, b1.b, acc1, 0, 0, 0);
    }
    __syncthreads();   // done with xin; reuse as ot
    #pragma unroll
    for (int r = 0; r < 4; ++r) {
        ot[(rt * 16 + (l >> 4) * 4 + r) * 68 + (ctb + 0) * 16 + (l & 15)] = acc0[r];
        ot[(rt * 16 + (l >> 4) * 4 + r) * 68 + (ctb + 1) * 16 + (l & 15)] = acc1[r];
    }
    __syncthreads();
    for (int v = t; v < 512; v += 256) {
        int node = v >> 4, q = v & 15;
        float4 bq = reinterpret_cast<const float4*>(eb)[q];
        float* p = &ot[node * 68 + q * 4];
        float4 o;
        o.x = silu_f(p[0] + bq.x); o.y = silu_f(p[1] + bq.y);
        o.z = silu_f(p[2] + bq.z); o.w = silu_f(p[3] + bq.w);
        int g = n0 + node;
        if (g < N) {
            reinterpret_cast<float4*>(x)[(size_t)g * 16 + q] = o;
            reinterpret_cast<float4*>(x0)[(size_t)g * 16 + q] = o;
        }
        p[0] = o.x; p[1] = o.y; p[2] = o.z; p[3] = o.w;
    }
    __syncthreads();
    {
        int node = t >> 3, j = t & 7;
        const float* p = &ot[node * 68 + j * 8];
        uint4 o;
        o.x = pack2(p[0], p[1]); o.y = pack2(p[2], p[3]);
        o.z = pack2(p[4], p[5]); o.w = pack2(p[6], p[7]);
        *reinterpret_cast<uint4*>(&xbuf[node * 72 + j * 8]) = o;
    }
    __syncthreads();
    #pragma unroll
    for (int mt = 0; mt < 2; ++mt) {
        U16 a0, a1, bA0, bA1, bB0, bB1;
        a0.u = *reinterpret_cast<const uint4*>(&xbuf[(mt * 16 + (l & 15)) * 72 + (l >> 4) * 8]);
        a1.u = *reinterpret_cast<const uint4*>(&xbuf[(mt * 16 + (l & 15)) * 72 + 32 + (l >> 4) * 8]);
        bA0.u = iFn[(w * 2 + 0) * 64 + l];
        bA1.u = iFn[(w * 2 + 1) * 64 + l];
        bB0.u = iFn[((w + 4) * 2 + 0) * 64 + l];
        bB1.u = iFn[((w + 4) * 2 + 1) * 64 + l];
        f32x4 accA = {0.f, 0.f, 0.f, 0.f}, accB = {0.f, 0.f, 0.f, 0.f};
        accA = __builtin_amdgcn_mfma_f32_16x16x32_bf16(a0.b, bA0.b, accA, 0, 0, 0);
        accA = __builtin_amdgcn_mfma_f32_16x16x32_bf16(a1.b, bA1.b, accA, 0, 0, 0);
        accB = __builtin_amdgcn_mfma_f32_16x16x32_bf16(a0.b, bB0.b, accB, 0, 0, 0);
        accB = __builtin_amdgcn_mfma_f32_16x16x32_bf16(a1.b, bB1.b, accB, 0, 0, 0);
        const int colA = w * 16 + (l & 15);
        const float biasA = ibn[colA];
        #pragma unroll
        for (int r = 0; r < 4; ++r) {
            int gn = n0 + mt * 16 + (l >> 4) * 4 + r;
            if (gn < N) {
                Aout[(size_t)gn * 64 + colA] = (unsigned short)bf16r(accA[r] + biasA);
                Bout[(size_t)gn * 64 + colA] = (unsigned short)bf16r(accB[r]);
            }
        }
    }
}

// ---------------- Fused edge + MFMA update + next-layer interact (+ final out) ----------------
template <bool LAST>
__global__ __launch_bounds__(256) void k_edge_upd(
    const int* __restrict__ rp, const int* __restrict__ col,
    const unsigned* __restrict__ Ab, const unsigned* __restrict__ Bb,
    float* __restrict__ x,
    const uint4* __restrict__ uFf, const float* __restrict__ ub,
    const uint4* __restrict__ iFn, const float* __restrict__ ibn,
    unsigned short* __restrict__ Aout, unsigned short* __restrict__ Bout,
    const float* __restrict__ x0, const float* __restrict__ oW, const float* __restrict__ ob,
    float* __restrict__ out, int N)
{
    __shared__ unsigned short vb[16 * 72];   // bf16 rows, stride 72
    __shared__ float sv[16 * 68];            // silu(update) rows, stride 68
    const int t = threadIdx.x;
    const int g = t >> 4, q = t & 15;
    const int w = t >> 6, l = t & 63;
    const int node = blockIdx.x * 16 + g;
    const bool valid = node < N;
    const size_t nidx = (size_t)(valid ? node : 0) * 16 + q;
    const uint2* __restrict__ Avb = reinterpret_cast<const uint2*>(Ab);
    const uint2* __restrict__ Bv = reinterpret_cast<const uint2*>(Bb);
    float4* __restrict__ Xv = reinterpret_cast<float4*>(x);

    const float4 a = unpack4(Avb[nidx]);
    const float4 xq = Xv[nidx];
    const int beg = valid ? rp[node] : 0;
    const int end = valid ? rp[node + 1] : 0;

    float4 acc = make_float4(0.f, 0.f, 0.f, 0.f);
    int j = beg;
    for (; j + 4 <= end; j += 4) {
        int d0 = col[j], d1 = col[j + 1], d2 = col[j + 2], d3 = col[j + 3];
        float4 b0 = unpack4(Bv[(size_t)d0 * 16 + q]);
        float4 b1 = unpack4(Bv[(size_t)d1 * 16 + q]);
        float4 b2 = unpack4(Bv[(size_t)d2 * 16 + q]);
        float4 b3 = unpack4(Bv[(size_t)d3 * 16 + q]);
        acc.x += silu_f(a.x + b0.x) + silu_f(a.x + b1.x) + silu_f(a.x + b2.x) + silu_f(a.x + b3.x);
        acc.y += silu_f(a.y + b0.y) + silu_f(a.y + b1.y) + silu_f(a.y + b2.y) + silu_f(a.y + b3.y);
        acc.z += silu_f(a.z + b0.z) + silu_f(a.z + b1.z) + silu_f(a.z + b2.z) + silu_f(a.z + b3.z);
        acc.w += silu_f(a.w + b0.w) + silu_f(a.w + b1.w) + silu_f(a.w + b2.w) + silu_f(a.w + b3.w);
    }
    for (; j < end; ++j) {
        int d = col[j];
        float4 b = unpack4(Bv[(size_t)d * 16 + q]);
        acc.x += silu_f(a.x + b.x); acc.y += silu_f(a.y + b.y);
        acc.z += silu_f(a.z + b.z); acc.w += silu_f(a.w + b.w);
    }
    float4 v;
    v.x = fmaf(0.25f, acc.x, xq.x); v.y = fmaf(0.25f, acc.y, xq.y);
    v.z = fmaf(0.25f, acc.z, xq.z); v.w = fmaf(0.25f, acc.w, xq.w);
    {
        uint2 vo;
        vo.x = pack2(v.x, v.y);
        vo.y = pack2(v.z, v.w);
        *reinterpret_cast<uint2*>(&vb[g * 72 + q * 4]) = vo;
    }
    __syncthreads();
    {
        U16 a0, a1, b0, b1;
        a0.u = *reinterpret_cast<const uint4*>(&vb[(l & 15) * 72 + (l >> 4) * 8]);
        a1.u = *reinterpret_cast<const uint4*>(&vb[(l & 15) * 72 + 32 + (l >> 4) * 8]);
        b0.u = uFf[(w * 2 + 0) * 64 + l];
        b1.u = uFf[(w * 2 + 1) * 64 + l];
        f32x4 uacc = {0.f, 0.f, 0.f, 0.f};
        uacc = __builtin_amdgcn_mfma_f32_16x16x32_bf16(a0.b, b0.b, uacc, 0, 0, 0);
        uacc = __builtin_amdgcn_mfma_f32_16x16x32_bf16(a1.b, b1.b, uacc, 0, 0, 0);
        const int h = w * 16 + (l & 15);
        const float ubh = ub[h];
        #pragma unroll
        for (int r = 0; r < 4; ++r)
            sv[((l >> 4) * 4 + r) * 68 + h] = silu_f(uacc[r] + ubh);
    }
    __syncthreads();
    const float4 s = *reinterpret_cast<const float4*>(&sv[g * 68 + q * 4]);
    float4 xn;
    xn.x = xq.x + s.x; xn.y = xq.y + s.y;
    xn.z = xq.z + s.z; xn.w = xq.w + s.w;
    if (valid && !LAST) Xv[nidx] = xn;
    if (!LAST) {
        uint2 xo;
        xo.x = pack2(xn.x, xn.y);
        xo.y = pack2(xn.z, xn.w);
        *reinterpret_cast<uint2*>(&vb[g * 72 + q * 4]) = xo;
        __syncthreads();
        U16 a0, a1, bA0, bA1, bB0, bB1;
        a0.u = *reinterpret_cast<const uint4*>(&vb[(l & 15) * 72 + (l >> 4) * 8]);
        a1.u = *reinterpret_cast<const uint4*>(&vb[(l & 15) * 72 + 32 + (l >> 4) * 8]);
        bA0.u = iFn[(w * 2 + 0) * 64 + l];
        bA1.u = iFn[(w * 2 + 1) * 64 + l];
        bB0.u = iFn[((w + 4) * 2 + 0) * 64 + l];
        bB1.u = iFn[((w + 4) * 2 + 1) * 64 + l];
        f32x4 accA = {0.f, 0.f, 0.f, 0.f}, accB = {0.f, 0.f, 0.f, 0.f};
        accA = __builtin_amdgcn_mfma_f32_16x16x32_bf16(a0.b, bA0.b, accA, 0, 0, 0);
        accA = __builtin_amdgcn_mfma_f32_16x16x32_bf16(a1.b, bA1.b, accA, 0, 0, 0);
        accB = __builtin_amdgcn_mfma_f32_16x16x32_bf16(a0.b, bB0.b, accB, 0, 0, 0);
        accB = __builtin_amdgcn_mfma_f32_16x16x32_bf16(a1.b, bB1.b, accB, 0, 0, 0);
        const int colA = w * 16 + (l & 15);
        const float biasA = ibn[colA];
        #pragma unroll
        for (int r = 0; r < 4; ++r) {
            int gn = blockIdx.x * 16 + (l >> 4) * 4 + r;
            if (gn < N) {
                Aout[(size_t)gn * 64 + colA] = (unsigned short)bf16r(accA[r] + biasA);
                Bout[(size_t)gn * 64 + colA] = (unsigned short)bf16r(accB[r]);
            }
        }
    } else {
        const float4 x0q = reinterpret_cast<const float4*>(x0)[nidx];
        float f0 = xn.x + x0q.x, f1 = xn.y + x0q.y, f2 = xn.z + x0q.z, f3 = xn.w + x0q.w;
        float p0 = 0.f, p1 = 0.f, p2 = 0.f;
        const int k0 = 4 * q;
        p0 = fmaf(f0, oW[(k0 + 0) * 3 + 0], p0); p1 = fmaf(f0, oW[(k0 + 0) * 3 + 1], p1); p2 = fmaf(f0, oW[(k0 + 0) * 3 + 2], p2);
        p0 = fmaf(f1, oW[(k0 + 1) * 3 + 0], p0); p1 = fmaf(f1, oW[(k0 + 1) * 3 + 1], p1); p2 = fmaf(f1, oW[(k0 + 1) * 3 + 2], p2);
        p0 = fmaf(f2, oW[(k0 + 2) * 3 + 0], p0); p1 = fmaf(f2, oW[(k0 + 2) * 3 + 1], p1); p2 = fmaf(f2, oW[(k0 + 2) * 3 + 2], p2);
        p0 = fmaf(f3, oW[(k0 + 3) * 3 + 0], p0); p1 = fmaf(f3, oW[(k0 + 3) * 3 + 1], p1); p2 = fmaf(f3, oW[(k0 + 3) * 3 + 2], p2);
        #pragma unroll
        for (int off = 8; off; off >>= 1) {
            p0 += __shfl_xor(p0, off, 16);
            p1 += __shfl_xor(p1, off, 16);
            p2 += __shfl_xor(p2, off, 16);
        }
        if (valid && q == 0) {
            out[node * 3 + 0] = p0 + ob[0];
            out[node * 3 + 1] = p1 + ob[1];
            out[node * 3 + 2] = p2 + ob[2];
        }
    }
}

extern "C" void kernel_launch(void* const* d_in, const int* in_sizes, int n_in,
                              void* d_out, int out_size, void* d_ws, size_t ws_size,
                              hipStream_t stream)
{
    const float* oneh = (const float*)d_in[0];
    const float* pos  = (const float*)d_in[1];
    const int*   ei   = (const int*)d_in[2];
    const float* embW = (const float*)d_in[3];
    const float* embB = (const float*)d_in[4];
    const float* iW   = (const float*)d_in[5];   // [4][128][64]
    const float* iB   = (const float*)d_in[6];   // [4][64]
    const float* uW   = (const float*)d_in[7];   // [4][64][64]
    const float* uB   = (const float*)d_in[8];   // [4][64]
    const float* oW   = (const float*)d_in[9];   // [64][3]
    const float* oB   = (const float*)d_in[10];  // [3]

    const int N = in_sizes[0] / 118;
    const int E = in_sizes[2] / 2;
    const int* src = ei;
    const int* dst = ei + E;

    float* ws = (float*)d_ws;
    const size_t NH = (size_t)N * H;
    float* x  = ws;
    float* x0 = ws + NH;
    unsigned short* A0   = (unsigned short*)(ws + 2 * NH);   // NH bf16
    unsigned short* A1   = A0 + NH;                           // NH bf16
    unsigned short* Bb0  = A1 + NH;                           // NH bf16
    unsigned short* Bb1  = Bb0 + NH;                          // NH bf16
    unsigned short* embF = Bb1 + NH;                          // 8192
    unsigned short* iF   = embF + 8192;                       // 32768
    unsigned short* uFf  = iF + 32768;                        // 16384
    int* ibase = (int*)(uFf + 16384);
    int* rp    = ibase;               // N+1
    int* col   = ibase + N + 1;       // E
    int* bbase = col + E;             // NB+1
    int* bcur  = bbase + 257;         // NB
    int* bpart = bcur + 256;          // 128*256
    uint2* tmp = (uint2*)(bpart + 128 * 256);  // E (own buffer: embed runs concurrently)

    const int nbm = (N + 31) / 32;
    const int nbf = (N + 15) / 16;
    const int NB  = (N + 255) / 256;

    // prep (weight pack || bucket partial counts) -> bucket bases -> bucketize
    k_prep<<<256, 256, 0, stream>>>(embW, iW, uW, embF, iF, uFf, src, bpart, E);
    k_bscan<<<1, 256, 0, stream>>>(bpart, bbase, bcur, NB, E);
    k_bucketA<<<(E + ACHUNK - 1) / ACHUNK, 256, 0, stream>>>(src, dst, bcur, tmp, E);
    // CSR finalize (bucket-local scan gives global offsets) || embed + layer-0 interact
    k_csr_embed<<<NB + nbm, 256, 0, stream>>>(tmp, bbase, rp, col, NB, E,
                                              oneh, pos, (const uint4*)embF, embB,
                                              (const uint4*)iF, iB, x, x0, A0, Bb0, N);

    unsigned short* Ain[4]  = {A0, A1, A0, A1};
    unsigned short* Aout[4] = {A1, A0, A1, A0};
    unsigned short* Bin[4]  = {Bb0, Bb1, Bb0, Bb1};
    unsigned short* Bout[4] = {Bb1, Bb0, Bb1, Bb0};

    for (int l = 0; l < 4; ++l) {
        const uint4* uFl = (const uint4*)(uFf + (size_t)l * 4096);
        const uint4* iFn = (l < 3) ? (const uint4*)(iF + (size_t)(l + 1) * 8192) : (const uint4*)iF;
        const float* ibn = (l < 3) ? iB + (l + 1) * 64 : iB;
        if (l < 3)
            k_edge_upd<false><<<nbf, 256, 0, stream>>>(rp, col, (const unsigned*)Ain[l], (const unsigned*)Bin[l], x,
                uFl, uB + l * 64, iFn, ibn, Aout[l], Bout[l], x0, oW, oB, (float*)d_out, N);
        else
            k_edge_upd<true><<<nbf, 256, 0, stream>>>(rp, col, (const unsigned*)Ain[l], (const unsigned*)Bin[l], x,
                uFl, uB + l * 64, iFn, ibn, Aout[l], Bout[l], x0, oW, oB, (float*)d_out, N);
    }
}